// Round 1
// baseline (933.588 us; speedup 1.0000x reference)
//
#include <hip/hip_runtime.h>
#include <hip/hip_bf16.h>
#include <cstdint>

#define NN 50000
#define NE 800000
#define FIN 128
#define FF 64
#define NG 64

// ---------------- CSR build ----------------

__global__ void k_degree(const int* __restrict__ dst, int* __restrict__ deg, int E) {
    int i = blockIdx.x * blockDim.x + threadIdx.x;
    if (i < E) atomicAdd(&deg[dst[i]], 1);
}

// single-block hierarchical exclusive scan: offs[0]=0, offs[i+1]=sum(deg[0..i])
__global__ void k_scan(const int* __restrict__ deg, int* __restrict__ offs, int n) {
    __shared__ int wsum[16];
    __shared__ int carry_s;
    int tid = threadIdx.x;
    int lane = tid & 63, wv = tid >> 6;
    if (tid == 0) { carry_s = 0; offs[0] = 0; }
    __syncthreads();
    for (int base = 0; base < n; base += 1024) {
        int i = base + tid;
        int v = (i < n) ? deg[i] : 0;
        // wave inclusive scan
        int s = v;
        #pragma unroll
        for (int off = 1; off < 64; off <<= 1) {
            int t = __shfl_up(s, off);
            if (lane >= off) s += t;
        }
        if (lane == 63) wsum[wv] = s;
        __syncthreads();
        if (wv == 0 && lane < 16) {
            int t = wsum[lane];
            #pragma unroll
            for (int off = 1; off < 16; off <<= 1) {
                int u = __shfl_up(t, off);
                if (lane >= off) t += u;
            }
            wsum[lane] = t;
        }
        __syncthreads();
        int wpre = (wv == 0) ? 0 : wsum[wv - 1];
        int total = wsum[15];
        int c0 = carry_s;
        if (i < n) offs[i + 1] = c0 + wpre + s;
        __syncthreads();
        if (tid == 0) carry_s = c0 + total;
        __syncthreads();
    }
}

__global__ void k_scatter(const int* __restrict__ ei, const float* __restrict__ euclid,
                          const int* __restrict__ offs, int* __restrict__ cursor,
                          int* __restrict__ csr_src, float* __restrict__ csr_w, int E) {
    int e = blockIdx.x * blockDim.x + threadIdx.x;
    if (e < E) {
        int s = ei[e];
        int d = ei[NE + e];
        int pos = offs[d] + atomicAdd(&cursor[d], 1);
        csr_src[pos] = s;
        csr_w[pos] = euclid[e];
    }
}

// ---------------- fused dual GEMM: xl = X@Wl+bl, xr = X@Wr+br ----------------
// block = 256 (4 waves); lane = output channel (64); one row per wave per iter.
// W staged in LDS packed as float4 over k: sW[kq*64+o] = (W[4kq][o],...,W[4kq+3][o])

template <int DIN>
__global__ __launch_bounds__(256) void k_gemm(
    const float* __restrict__ X,
    const float* __restrict__ Wl, const float* __restrict__ bl,
    const float* __restrict__ Wr, const float* __restrict__ br,
    float* __restrict__ xl, float* __restrict__ xr, int n) {
    __shared__ float4 sWl[(DIN / 4) * 64];
    __shared__ float4 sWr[(DIN / 4) * 64];
    int tid = threadIdx.x;
    for (int i = tid; i < (DIN / 4) * 64; i += blockDim.x) {
        int kq = i >> 6, o = i & 63;
        sWl[i] = make_float4(Wl[(4 * kq + 0) * 64 + o], Wl[(4 * kq + 1) * 64 + o],
                             Wl[(4 * kq + 2) * 64 + o], Wl[(4 * kq + 3) * 64 + o]);
        sWr[i] = make_float4(Wr[(4 * kq + 0) * 64 + o], Wr[(4 * kq + 1) * 64 + o],
                             Wr[(4 * kq + 2) * 64 + o], Wr[(4 * kq + 3) * 64 + o]);
    }
    __syncthreads();
    int lane = tid & 63, wv = tid >> 6;
    int nw = blockDim.x >> 6;
    float bll = bl[lane], brr = br[lane];
    for (int row = blockIdx.x * nw + wv; row < n; row += gridDim.x * nw) {
        const float4* x4 = (const float4*)(X + (size_t)row * DIN);
        float al = bll, ar = brr;
        #pragma unroll 4
        for (int kq = 0; kq < DIN / 4; kq++) {
            float4 xv = x4[kq];
            float4 wl = sWl[kq * 64 + lane];
            float4 wr = sWr[kq * 64 + lane];
            al += xv.x * wl.x + xv.y * wl.y + xv.z * wl.z + xv.w * wl.w;
            ar += xv.x * wr.x + xv.y * wr.y + xv.z * wr.z + xv.w * wr.w;
        }
        xl[(size_t)row * 64 + lane] = al;
        xr[(size_t)row * 64 + lane] = ar;
    }
}

// ---------------- edge kernel: one wave per destination node ----------------
// lane = feature channel (64). Pass 1: online softmax over incident edges
// (logits cached in LDS, cap 128). Pass 2: acc += alpha * xl[src].

#define PCAP 128

__device__ __forceinline__ float wave_sum(float p) {
    #pragma unroll
    for (int off = 32; off > 0; off >>= 1) p += __shfl_xor(p, off);
    return p;
}

__global__ __launch_bounds__(256) void k_edge(
    const float* __restrict__ xl, const float* __restrict__ xr,
    const int* __restrict__ offs, const int* __restrict__ csr_src,
    const float* __restrict__ csr_w,
    const float* __restrict__ We, const float* __restrict__ att,
    const float* __restrict__ cb, float* __restrict__ hout, int n) {
    __shared__ float pbuf[4][PCAP];
    int gtid = blockIdx.x * blockDim.x + threadIdx.x;
    int wv = gtid >> 6;
    int lwv = threadIdx.x >> 6;
    int lane = threadIdx.x & 63;
    if (wv >= n) return;
    int d = wv;
    float xr_l = xr[(size_t)d * 64 + lane];
    float We_l = We[lane], att_l = att[lane], c_l = cb[lane];
    int s0 = offs[d], s1 = offs[d + 1];

    float mx = -INFINITY, sum = 0.f;
    for (int e = s0; e < s1; e++) {
        int s = csr_src[e];
        float w = csr_w[e];
        float m = xl[(size_t)s * 64 + lane] + xr_l + w * We_l;
        m = m > 0.f ? m : 0.2f * m;
        float p = wave_sum(m * att_l);
        int idx = e - s0;
        if (idx < PCAP && lane == 0) pbuf[lwv][idx] = p;
        float nm = fmaxf(mx, p);
        sum = sum * __expf(mx - nm) + __expf(p - nm);
        mx = nm;
    }

    float inv = (s1 > s0) ? 1.0f / sum : 0.f;
    float acc = 0.f;
    for (int e = s0; e < s1; e++) {
        int s = csr_src[e];
        float xls = xl[(size_t)s * 64 + lane];
        int idx = e - s0;
        float p;
        if (idx < PCAP) {
            p = pbuf[lwv][idx];
        } else {
            float w = csr_w[e];
            float m = xls + xr_l + w * We_l;
            m = m > 0.f ? m : 0.2f * m;
            p = wave_sum(m * att_l);
        }
        acc += __expf(p - mx) * inv * xls;
    }
    float o = acc + c_l;
    hout[(size_t)d * 64 + lane] = o > 0.f ? o : 0.f;
}

// ---------------- pooling + linear + softmax ----------------

__global__ __launch_bounds__(64) void k_pool(
    const float* __restrict__ h, const int* __restrict__ batch,
    const float* __restrict__ Wlin, const float* __restrict__ blin,
    float* __restrict__ out, int n) {
    int g = blockIdx.x;
    int lane = threadIdx.x;
    // lower_bound(batch, g) and lower_bound(batch, g+1)
    int lo = 0, hi = n;
    while (lo < hi) { int mid = (lo + hi) >> 1; if (batch[mid] < g) lo = mid + 1; else hi = mid; }
    int start = lo;
    lo = start; hi = n;
    while (lo < hi) { int mid = (lo + hi) >> 1; if (batch[mid] < g + 1) lo = mid + 1; else hi = mid; }
    int end = lo;
    float acc = 0.f;
    for (int i = start; i < end; i++) acc += h[(size_t)i * 64 + lane];
    int cnt = end - start;
    float pooled = acc / (float)(cnt > 0 ? cnt : 1);
    float p0 = pooled * Wlin[lane * 2 + 0];
    float p1 = pooled * Wlin[lane * 2 + 1];
    #pragma unroll
    for (int off = 32; off > 0; off >>= 1) {
        p0 += __shfl_xor(p0, off);
        p1 += __shfl_xor(p1, off);
    }
    if (lane == 0) {
        p0 += blin[0]; p1 += blin[1];
        float m = fmaxf(p0, p1);
        float e0 = __expf(p0 - m), e1 = __expf(p1 - m);
        float s = e0 + e1;
        out[g * 2 + 0] = e0 / s;
        out[g * 2 + 1] = e1 / s;
    }
}

// ---------------- launch ----------------

extern "C" void kernel_launch(void* const* d_in, const int* in_sizes, int n_in,
                              void* d_out, int out_size, void* d_ws, size_t ws_size,
                              hipStream_t stream) {
    const float* x      = (const float*)d_in[0];
    const int*   ei     = (const int*)d_in[1];
    const float* euclid = (const float*)d_in[2];
    const int*   batch  = (const int*)d_in[3];
    auto P = [&](int i) { return (const float*)d_in[i]; };

    uintptr_t base = (uintptr_t)d_ws;
    auto carve = [&](size_t bytes) {
        uintptr_t r = base;
        base += (bytes + 255) & ~(size_t)255;
        return (void*)r;
    };
    float* xl      = (float*)carve((size_t)NN * 64 * 4);
    float* xr      = (float*)carve((size_t)NN * 64 * 4);
    float* h1      = (float*)carve((size_t)NN * 64 * 4);
    float* h2      = (float*)carve((size_t)NN * 64 * 4);
    int*   deg     = (int*)carve((size_t)NN * 4);
    int*   offs    = (int*)carve((size_t)(NN + 1) * 4);
    int*   cursor  = (int*)carve((size_t)NN * 4);
    int*   csr_src = (int*)carve((size_t)NE * 4);
    float* csr_w   = (float*)carve((size_t)NE * 4);

    hipMemsetAsync(deg, 0, (size_t)NN * 4, stream);
    hipMemsetAsync(cursor, 0, (size_t)NN * 4, stream);

    k_degree<<<(NE + 255) / 256, 256, 0, stream>>>(ei + NE, deg, NE);
    k_scan<<<1, 1024, 0, stream>>>(deg, offs, NN);
    k_scatter<<<(NE + 255) / 256, 256, 0, stream>>>(ei, euclid, offs, cursor, csr_src, csr_w, NE);

    // layer 1: x [NN,128]
    k_gemm<128><<<512, 256, 0, stream>>>(x, P(4), P(5), P(6), P(7), xl, xr, NN);
    k_edge<<<(NN + 3) / 4, 256, 0, stream>>>(xl, xr, offs, csr_src, csr_w, P(8), P(9), P(10), h1, NN);
    // layer 2
    k_gemm<64><<<1024, 256, 0, stream>>>(h1, P(11), P(12), P(13), P(14), xl, xr, NN);
    k_edge<<<(NN + 3) / 4, 256, 0, stream>>>(xl, xr, offs, csr_src, csr_w, P(15), P(16), P(17), h2, NN);
    // layer 3
    k_gemm<64><<<1024, 256, 0, stream>>>(h2, P(18), P(19), P(20), P(21), xl, xr, NN);
    k_edge<<<(NN + 3) / 4, 256, 0, stream>>>(xl, xr, offs, csr_src, csr_w, P(22), P(23), P(24), h1, NN);

    k_pool<<<NG, 64, 0, stream>>>(h1, batch, P(25), P(26), (float*)d_out, NN);
}

// Round 2
// 555.295 us; speedup vs baseline: 1.6812x; 1.6812x over previous
//
#include <hip/hip_runtime.h>
#include <hip/hip_bf16.h>
#include <cstdint>

#define NN 50000
#define NE 800000
#define NG 64

// ---------------- CSR build ----------------

__global__ void k_degree(const int* __restrict__ dst, int* __restrict__ deg, int E) {
    int i = blockIdx.x * blockDim.x + threadIdx.x;
    if (i < E) atomicAdd(&deg[dst[i]], 1);
}

// single-block hierarchical exclusive scan: offs[0]=0, offs[i+1]=sum(deg[0..i])
__global__ void k_scan(const int* __restrict__ deg, int* __restrict__ offs, int n) {
    __shared__ int wsum[16];
    __shared__ int carry_s;
    int tid = threadIdx.x;
    int lane = tid & 63, wv = tid >> 6;
    if (tid == 0) { carry_s = 0; offs[0] = 0; }
    __syncthreads();
    for (int base = 0; base < n; base += 1024) {
        int i = base + tid;
        int v = (i < n) ? deg[i] : 0;
        int s = v;
        #pragma unroll
        for (int off = 1; off < 64; off <<= 1) {
            int t = __shfl_up(s, off);
            if (lane >= off) s += t;
        }
        if (lane == 63) wsum[wv] = s;
        __syncthreads();
        if (wv == 0 && lane < 16) {
            int t = wsum[lane];
            #pragma unroll
            for (int off = 1; off < 16; off <<= 1) {
                int u = __shfl_up(t, off);
                if (lane >= off) t += u;
            }
            wsum[lane] = t;
        }
        __syncthreads();
        int wpre = (wv == 0) ? 0 : wsum[wv - 1];
        int total = wsum[15];
        int c0 = carry_s;
        if (i < n) offs[i + 1] = c0 + wpre + s;
        __syncthreads();
        if (tid == 0) carry_s = c0 + total;
        __syncthreads();
    }
}

__global__ void k_scatter(const int* __restrict__ ei, const float* __restrict__ euclid,
                          const int* __restrict__ offs, int* __restrict__ cursor,
                          int* __restrict__ csr_src, float* __restrict__ csr_w, int E) {
    int e = blockIdx.x * blockDim.x + threadIdx.x;
    if (e < E) {
        int s = ei[e];
        int d = ei[NE + e];
        int pos = offs[d] + atomicAdd(&cursor[d], 1);
        csr_src[pos] = s;
        csr_w[pos] = euclid[e];
    }
}

// ---------------- fused dual GEMM: xl = X@Wl+bl, xr = X@Wr+br ----------------

template <int DIN>
__global__ __launch_bounds__(256) void k_gemm(
    const float* __restrict__ X,
    const float* __restrict__ Wl, const float* __restrict__ bl,
    const float* __restrict__ Wr, const float* __restrict__ br,
    float* __restrict__ xl, float* __restrict__ xr, int n) {
    __shared__ float4 sWl[(DIN / 4) * 64];
    __shared__ float4 sWr[(DIN / 4) * 64];
    int tid = threadIdx.x;
    for (int i = tid; i < (DIN / 4) * 64; i += blockDim.x) {
        int kq = i >> 6, o = i & 63;
        sWl[i] = make_float4(Wl[(4 * kq + 0) * 64 + o], Wl[(4 * kq + 1) * 64 + o],
                             Wl[(4 * kq + 2) * 64 + o], Wl[(4 * kq + 3) * 64 + o]);
        sWr[i] = make_float4(Wr[(4 * kq + 0) * 64 + o], Wr[(4 * kq + 1) * 64 + o],
                             Wr[(4 * kq + 2) * 64 + o], Wr[(4 * kq + 3) * 64 + o]);
    }
    __syncthreads();
    int lane = tid & 63, wv = tid >> 6;
    int nw = blockDim.x >> 6;
    float bll = bl[lane], brr = br[lane];
    for (int row = blockIdx.x * nw + wv; row < n; row += gridDim.x * nw) {
        const float4* x4 = (const float4*)(X + (size_t)row * DIN);
        float al = bll, ar = brr;
        #pragma unroll 4
        for (int kq = 0; kq < DIN / 4; kq++) {
            float4 xv = x4[kq];
            float4 wl = sWl[kq * 64 + lane];
            float4 wr = sWr[kq * 64 + lane];
            al += xv.x * wl.x + xv.y * wl.y + xv.z * wl.z + xv.w * wl.w;
            ar += xv.x * wr.x + xv.y * wr.y + xv.z * wr.z + xv.w * wr.w;
        }
        xl[(size_t)row * 64 + lane] = al;
        xr[(size_t)row * 64 + lane] = ar;
    }
}

// ---------------- edge kernel: one wave per destination node ----------------
// Pass 1: logits in chunks of 4 (4 gathers in flight, 4 interleaved shfl
// butterflies) -> per-wave LDS. Then ONE max-butterfly + ONE expsum-butterfly
// per node; normalized alpha written back to LDS. Pass 2: pure gather+FMA.

#define PCAP 128

__device__ __forceinline__ float wave_sum(float p) {
    #pragma unroll
    for (int off = 32; off > 0; off >>= 1) p += __shfl_xor(p, off);
    return p;
}

__device__ __forceinline__ void wave_sum4(float& a, float& b, float& c, float& d) {
    #pragma unroll
    for (int off = 32; off > 0; off >>= 1) {
        a += __shfl_xor(a, off);
        b += __shfl_xor(b, off);
        c += __shfl_xor(c, off);
        d += __shfl_xor(d, off);
    }
}

__global__ __launch_bounds__(256) void k_edge(
    const float* __restrict__ xl, const float* __restrict__ xr,
    const int* __restrict__ offs, const int* __restrict__ csr_src,
    const float* __restrict__ csr_w,
    const float* __restrict__ We, const float* __restrict__ att,
    const float* __restrict__ cb, float* __restrict__ hout, int n) {
    __shared__ float pbuf[4][PCAP];
    int gtid = blockIdx.x * blockDim.x + threadIdx.x;
    int d = gtid >> 6;
    int lwv = threadIdx.x >> 6;
    int lane = threadIdx.x & 63;
    if (d >= n) return;
    float xr_l = xr[(size_t)d * 64 + lane];
    float We_l = We[lane], att_l = att[lane], c_l = cb[lane];
    int s0 = offs[d], s1 = offs[d + 1];
    int deg = s1 - s0;
    float acc = 0.f;

    if (deg > 0 && deg <= PCAP) {
        // phase 1: all logits -> LDS (chunks of 4, clamped index, no divergence)
        for (int base = 0; base < deg; base += 4) {
            int iA = base, iB = min(base + 1, deg - 1);
            int iC = min(base + 2, deg - 1), iD = min(base + 3, deg - 1);
            int sA = csr_src[s0 + iA], sB = csr_src[s0 + iB];
            int sC = csr_src[s0 + iC], sD = csr_src[s0 + iD];
            float wA = csr_w[s0 + iA], wB = csr_w[s0 + iB];
            float wC = csr_w[s0 + iC], wD = csr_w[s0 + iD];
            float mA = xl[(size_t)sA * 64 + lane] + xr_l + wA * We_l;
            float mB = xl[(size_t)sB * 64 + lane] + xr_l + wB * We_l;
            float mC = xl[(size_t)sC * 64 + lane] + xr_l + wC * We_l;
            float mD = xl[(size_t)sD * 64 + lane] + xr_l + wD * We_l;
            mA = (mA > 0.f ? mA : 0.2f * mA) * att_l;
            mB = (mB > 0.f ? mB : 0.2f * mB) * att_l;
            mC = (mC > 0.f ? mC : 0.2f * mC) * att_l;
            mD = (mD > 0.f ? mD : 0.2f * mD) * att_l;
            wave_sum4(mA, mB, mC, mD);
            if (lane == 0) {
                pbuf[lwv][iA] = mA; pbuf[lwv][iB] = mB;
                pbuf[lwv][iC] = mC; pbuf[lwv][iD] = mD;
            }
        }
        // phase 2: one max-reduce + one expsum-reduce over buffered logits
        float pm = -INFINITY;
        for (int i = lane; i < deg; i += 64) pm = fmaxf(pm, pbuf[lwv][i]);
        #pragma unroll
        for (int off = 32; off > 0; off >>= 1) pm = fmaxf(pm, __shfl_xor(pm, off));
        float se = 0.f;
        for (int i = lane; i < deg; i += 64) se += __expf(pbuf[lwv][i] - pm);
        se = wave_sum(se);
        float inv = 1.0f / se;
        for (int i = lane; i < deg; i += 64) pbuf[lwv][i] = __expf(pbuf[lwv][i] - pm) * inv;
        // pass 2: acc += alpha * xl[src], unrolled x4
        int e = s0;
        for (; e + 4 <= s1; e += 4) {
            int sA = csr_src[e], sB = csr_src[e + 1], sC = csr_src[e + 2], sD = csr_src[e + 3];
            float aA = pbuf[lwv][e - s0], aB = pbuf[lwv][e - s0 + 1];
            float aC = pbuf[lwv][e - s0 + 2], aD = pbuf[lwv][e - s0 + 3];
            acc += aA * xl[(size_t)sA * 64 + lane];
            acc += aB * xl[(size_t)sB * 64 + lane];
            acc += aC * xl[(size_t)sC * 64 + lane];
            acc += aD * xl[(size_t)sD * 64 + lane];
        }
        for (; e < s1; e++) {
            acc += pbuf[lwv][e - s0] * xl[(size_t)csr_src[e] * 64 + lane];
        }
    } else if (deg > PCAP) {
        // fallback: online softmax with recompute (never expected at these sizes)
        float mx = -INFINITY, sum = 0.f;
        for (int e = s0; e < s1; e++) {
            int s = csr_src[e];
            float w = csr_w[e];
            float m = xl[(size_t)s * 64 + lane] + xr_l + w * We_l;
            m = m > 0.f ? m : 0.2f * m;
            float p = wave_sum(m * att_l);
            float nm = fmaxf(mx, p);
            sum = sum * __expf(mx - nm) + __expf(p - nm);
            mx = nm;
        }
        float inv = 1.0f / sum;
        for (int e = s0; e < s1; e++) {
            int s = csr_src[e];
            float xls = xl[(size_t)s * 64 + lane];
            float w = csr_w[e];
            float m = xls + xr_l + w * We_l;
            m = m > 0.f ? m : 0.2f * m;
            float p = wave_sum(m * att_l);
            acc += __expf(p - mx) * inv * xls;
        }
    }
    float o = acc + c_l;
    hout[(size_t)d * 64 + lane] = o > 0.f ? o : 0.f;
}

// ---------------- pooling: grid-stride partial sums + tiny head ----------------

__global__ __launch_bounds__(256) void k_pool_partial(
    const float* __restrict__ h, const int* __restrict__ batch,
    float* __restrict__ sums, int n) {
    int wv = blockIdx.x * (blockDim.x >> 6) + (threadIdx.x >> 6);
    int lane = threadIdx.x & 63;
    int nwv = gridDim.x * (blockDim.x >> 6);
    int chunk = (n + nwv - 1) / nwv;
    int r0 = wv * chunk, r1 = min(n, r0 + chunk);
    if (r0 >= r1) return;
    float acc = 0.f;
    int g = batch[r0];
    for (int r = r0; r < r1; r++) {
        int bg = batch[r];
        if (bg != g) {
            atomicAdd(&sums[g * 64 + lane], acc);
            acc = 0.f;
            g = bg;
        }
        acc += h[(size_t)r * 64 + lane];
    }
    atomicAdd(&sums[g * 64 + lane], acc);
}

__global__ __launch_bounds__(64) void k_head(
    const float* __restrict__ sums, const int* __restrict__ batch,
    const float* __restrict__ Wlin, const float* __restrict__ blin,
    float* __restrict__ out, int n) {
    int g = blockIdx.x;
    int lane = threadIdx.x;
    int lo = 0, hi = n;
    while (lo < hi) { int mid = (lo + hi) >> 1; if (batch[mid] < g) lo = mid + 1; else hi = mid; }
    int start = lo;
    lo = start; hi = n;
    while (lo < hi) { int mid = (lo + hi) >> 1; if (batch[mid] < g + 1) lo = mid + 1; else hi = mid; }
    int cnt = lo - start;
    float pooled = sums[g * 64 + lane] / (float)(cnt > 0 ? cnt : 1);
    float p0 = pooled * Wlin[lane * 2 + 0];
    float p1 = pooled * Wlin[lane * 2 + 1];
    #pragma unroll
    for (int off = 32; off > 0; off >>= 1) {
        p0 += __shfl_xor(p0, off);
        p1 += __shfl_xor(p1, off);
    }
    if (lane == 0) {
        p0 += blin[0]; p1 += blin[1];
        float m = fmaxf(p0, p1);
        float e0 = __expf(p0 - m), e1 = __expf(p1 - m);
        float s = e0 + e1;
        out[g * 2 + 0] = e0 / s;
        out[g * 2 + 1] = e1 / s;
    }
}

// ---------------- launch ----------------

extern "C" void kernel_launch(void* const* d_in, const int* in_sizes, int n_in,
                              void* d_out, int out_size, void* d_ws, size_t ws_size,
                              hipStream_t stream) {
    const float* x      = (const float*)d_in[0];
    const int*   ei     = (const int*)d_in[1];
    const float* euclid = (const float*)d_in[2];
    const int*   batch  = (const int*)d_in[3];
    auto P = [&](int i) { return (const float*)d_in[i]; };

    uintptr_t base = (uintptr_t)d_ws;
    auto carve = [&](size_t bytes) {
        uintptr_t r = base;
        base += (bytes + 255) & ~(size_t)255;
        return (void*)r;
    };
    float* xl      = (float*)carve((size_t)NN * 64 * 4);
    float* xr      = (float*)carve((size_t)NN * 64 * 4);
    float* h1      = (float*)carve((size_t)NN * 64 * 4);
    float* h2      = (float*)carve((size_t)NN * 64 * 4);
    int*   deg     = (int*)carve((size_t)NN * 4);
    int*   offs    = (int*)carve((size_t)(NN + 1) * 4);
    int*   cursor  = (int*)carve((size_t)NN * 4);
    int*   csr_src = (int*)carve((size_t)NE * 4);
    float* csr_w   = (float*)carve((size_t)NE * 4);
    float* gsums   = (float*)carve((size_t)NG * 64 * 4);

    hipMemsetAsync(deg, 0, (size_t)NN * 4, stream);
    hipMemsetAsync(cursor, 0, (size_t)NN * 4, stream);
    hipMemsetAsync(gsums, 0, (size_t)NG * 64 * 4, stream);

    k_degree<<<(NE + 255) / 256, 256, 0, stream>>>(ei + NE, deg, NE);
    k_scan<<<1, 1024, 0, stream>>>(deg, offs, NN);
    k_scatter<<<(NE + 255) / 256, 256, 0, stream>>>(ei, euclid, offs, cursor, csr_src, csr_w, NE);

    // layer 1: x [NN,128]
    k_gemm<128><<<512, 256, 0, stream>>>(x, P(4), P(5), P(6), P(7), xl, xr, NN);
    k_edge<<<(NN + 3) / 4, 256, 0, stream>>>(xl, xr, offs, csr_src, csr_w, P(8), P(9), P(10), h1, NN);
    // layer 2
    k_gemm<64><<<1024, 256, 0, stream>>>(h1, P(11), P(12), P(13), P(14), xl, xr, NN);
    k_edge<<<(NN + 3) / 4, 256, 0, stream>>>(xl, xr, offs, csr_src, csr_w, P(15), P(16), P(17), h2, NN);
    // layer 3
    k_gemm<64><<<1024, 256, 0, stream>>>(h2, P(18), P(19), P(20), P(21), xl, xr, NN);
    k_edge<<<(NN + 3) / 4, 256, 0, stream>>>(xl, xr, offs, csr_src, csr_w, P(22), P(23), P(24), h1, NN);

    k_pool_partial<<<256, 256, 0, stream>>>(h1, batch, gsums, NN);
    k_head<<<NG, 64, 0, stream>>>(gsums, batch, P(25), P(26), (float*)d_out, NN);
}

// Round 3
// 444.823 us; speedup vs baseline: 2.0988x; 1.2484x over previous
//
#include <hip/hip_runtime.h>
#include <hip/hip_bf16.h>
#include <cstdint>

#define NN 50000
#define NE 800000
#define NG 64

// ---------------- CSR build ----------------

__global__ void k_degree(const int* __restrict__ dst, int* __restrict__ deg, int E) {
    int i = blockIdx.x * blockDim.x + threadIdx.x;
    if (i < E) atomicAdd(&deg[dst[i]], 1);
}

__global__ void k_scan(const int* __restrict__ deg, int* __restrict__ offs, int n) {
    __shared__ int wsum[16];
    __shared__ int carry_s;
    int tid = threadIdx.x;
    int lane = tid & 63, wv = tid >> 6;
    if (tid == 0) { carry_s = 0; offs[0] = 0; }
    __syncthreads();
    for (int base = 0; base < n; base += 1024) {
        int i = base + tid;
        int v = (i < n) ? deg[i] : 0;
        int s = v;
        #pragma unroll
        for (int off = 1; off < 64; off <<= 1) {
            int t = __shfl_up(s, off);
            if (lane >= off) s += t;
        }
        if (lane == 63) wsum[wv] = s;
        __syncthreads();
        if (wv == 0 && lane < 16) {
            int t = wsum[lane];
            #pragma unroll
            for (int off = 1; off < 16; off <<= 1) {
                int u = __shfl_up(t, off);
                if (lane >= off) t += u;
            }
            wsum[lane] = t;
        }
        __syncthreads();
        int wpre = (wv == 0) ? 0 : wsum[wv - 1];
        int total = wsum[15];
        int c0 = carry_s;
        if (i < n) offs[i + 1] = c0 + wpre + s;
        __syncthreads();
        if (tid == 0) carry_s = c0 + total;
        __syncthreads();
    }
}

__global__ void k_scatter(const int* __restrict__ ei, const float* __restrict__ euclid,
                          const int* __restrict__ offs, int* __restrict__ cursor,
                          int* __restrict__ csr_src, float* __restrict__ csr_w, int E) {
    int e = blockIdx.x * blockDim.x + threadIdx.x;
    if (e < E) {
        int s = ei[e];
        int d = ei[NE + e];
        int pos = offs[d] + atomicAdd(&cursor[d], 1);
        csr_src[pos] = s;
        csr_w[pos] = euclid[e];
    }
}

// ---------------- fused dual GEMM, 8-row register blocking per wave ----------
// lane = output channel (64). Per kq: 2 ds_read_b128 feed 64 FMAs (8 rows).
// X row loads are wave-uniform (broadcast; L1-resident row).

template <int DIN, int RB>
__global__ __launch_bounds__(256) void k_gemm(
    const float* __restrict__ X,
    const float* __restrict__ Wl, const float* __restrict__ bl,
    const float* __restrict__ Wr, const float* __restrict__ br,
    float* __restrict__ xl, float* __restrict__ xr, int n) {
    __shared__ float4 sWl[(DIN / 4) * 64];
    __shared__ float4 sWr[(DIN / 4) * 64];
    int tid = threadIdx.x;
    for (int i = tid; i < (DIN / 4) * 64; i += blockDim.x) {
        int kq = i >> 6, o = i & 63;
        sWl[i] = make_float4(Wl[(4 * kq + 0) * 64 + o], Wl[(4 * kq + 1) * 64 + o],
                             Wl[(4 * kq + 2) * 64 + o], Wl[(4 * kq + 3) * 64 + o]);
        sWr[i] = make_float4(Wr[(4 * kq + 0) * 64 + o], Wr[(4 * kq + 1) * 64 + o],
                             Wr[(4 * kq + 2) * 64 + o], Wr[(4 * kq + 3) * 64 + o]);
    }
    __syncthreads();
    int lane = tid & 63, wv = tid >> 6;
    float bll = bl[lane], brr = br[lane];
    for (int rb = (blockIdx.x * 4 + wv) * RB; rb < n; rb += gridDim.x * 4 * RB) {
        const float4* xp[RB];
        #pragma unroll
        for (int i = 0; i < RB; i++) {
            int ri = min(rb + i, n - 1);
            xp[i] = (const float4*)(X + (size_t)ri * DIN);
        }
        float al[RB], ar[RB];
        #pragma unroll
        for (int i = 0; i < RB; i++) { al[i] = bll; ar[i] = brr; }
        #pragma unroll 2
        for (int kq = 0; kq < DIN / 4; kq++) {
            float4 wl = sWl[kq * 64 + lane];
            float4 wr = sWr[kq * 64 + lane];
            #pragma unroll
            for (int i = 0; i < RB; i++) {
                float4 xv = xp[i][kq];
                al[i] += xv.x * wl.x + xv.y * wl.y + xv.z * wl.z + xv.w * wl.w;
                ar[i] += xv.x * wr.x + xv.y * wr.y + xv.z * wr.z + xv.w * wr.w;
            }
        }
        #pragma unroll
        for (int i = 0; i < RB; i++) {
            int ri = min(rb + i, n - 1);
            xl[(size_t)ri * 64 + lane] = al[i];
            xr[(size_t)ri * 64 + lane] = ar[i];
        }
    }
}

// ---------------- edge kernel: one wave per dst node, 4 edges x 16 lanes ----
// lane = (eg=lane>>4: edge sub 0..3, fg=lane&15: feature quad). One fused
// online-softmax pass: 1 gather of xl[src] per edge (float4 per lane),
// xor{1,2,4,8} butterfly reduces all 4 edges' dots at once (1 shfl/edge),
// group merge via xor{16,32} at the end.

__global__ __launch_bounds__(256) void k_edge(
    const float* __restrict__ xl, const float* __restrict__ xr,
    const int* __restrict__ offs, const int* __restrict__ csr_src,
    const float* __restrict__ csr_w,
    const float* __restrict__ We, const float* __restrict__ att,
    const float* __restrict__ cb, float* __restrict__ hout, int n) {
    const float NEGBIG = -1e30f;
    int gtid = blockIdx.x * blockDim.x + threadIdx.x;
    int d = gtid >> 6;
    if (d >= n) return;
    int lane = threadIdx.x & 63;
    int fg = lane & 15;   // feature quad index
    int eg = lane >> 4;   // edge sub-slot 0..3

    float4 c4 = *(const float4*)(cb + fg * 4);
    int s0 = offs[d], s1 = offs[d + 1];
    int deg = s1 - s0;
    if (deg == 0) {
        if (eg == 0) {
            float4 o = make_float4(fmaxf(c4.x, 0.f), fmaxf(c4.y, 0.f),
                                   fmaxf(c4.z, 0.f), fmaxf(c4.w, 0.f));
            *(float4*)(hout + (size_t)d * 64 + fg * 4) = o;
        }
        return;
    }
    float4 xr4 = *(const float4*)(xr + (size_t)d * 64 + fg * 4);
    float4 We4 = *(const float4*)(We + fg * 4);
    float4 at4 = *(const float4*)(att + fg * 4);

    float mx = NEGBIG, sum = 0.f;
    float4 acc = make_float4(0.f, 0.f, 0.f, 0.f);

    for (int base = 0; base < deg; base += 4) {
        int idx = base + eg;
        bool valid = idx < deg;
        int e = s0 + (valid ? idx : deg - 1);
        int s = csr_src[e];
        float w = csr_w[e];
        float4 xl4 = *(const float4*)(xl + (size_t)s * 64 + fg * 4);
        float mA = xl4.x + xr4.x + w * We4.x;
        float mB = xl4.y + xr4.y + w * We4.y;
        float mC = xl4.z + xr4.z + w * We4.z;
        float mD = xl4.w + xr4.w + w * We4.w;
        mA = (mA > 0.f ? mA : 0.2f * mA);
        mB = (mB > 0.f ? mB : 0.2f * mB);
        mC = (mC > 0.f ? mC : 0.2f * mC);
        mD = (mD > 0.f ? mD : 0.2f * mD);
        float p = mA * at4.x + mB * at4.y + mC * at4.z + mD * at4.w;
        // reduce across the 16 lanes of this edge group (all 4 groups at once)
        #pragma unroll
        for (int off = 1; off < 16; off <<= 1) p += __shfl_xor(p, off);
        // online update (p uniform within group)
        float nm = fmaxf(mx, valid ? p : NEGBIG);
        float f = __expf(mx - nm);           // mx=-1e30 -> underflow 0; mx==nm -> 1
        float wp = valid ? __expf(p - nm) : 0.f;
        acc.x = acc.x * f + wp * xl4.x;
        acc.y = acc.y * f + wp * xl4.y;
        acc.z = acc.z * f + wp * xl4.z;
        acc.w = acc.w * f + wp * xl4.w;
        sum = sum * f + wp;
        mx = nm;
    }

    // merge the 4 edge groups (xor 16, 32); state is uniform within a group
    #pragma unroll
    for (int off = 16; off <= 32; off <<= 1) {
        float omx = __shfl_xor(mx, off);
        float osum = __shfl_xor(sum, off);
        float oax = __shfl_xor(acc.x, off);
        float oay = __shfl_xor(acc.y, off);
        float oaz = __shfl_xor(acc.z, off);
        float oaw = __shfl_xor(acc.w, off);
        float nm = fmaxf(mx, omx);
        float f1 = __expf(mx - nm);
        float f2 = __expf(omx - nm);
        acc.x = acc.x * f1 + oax * f2;
        acc.y = acc.y * f1 + oay * f2;
        acc.z = acc.z * f1 + oaz * f2;
        acc.w = acc.w * f1 + oaw * f2;
        sum = sum * f1 + osum * f2;
        mx = nm;
    }

    if (eg == 0) {
        float inv = 1.0f / sum;
        float4 o;
        o.x = fmaxf(acc.x * inv + c4.x, 0.f);
        o.y = fmaxf(acc.y * inv + c4.y, 0.f);
        o.z = fmaxf(acc.z * inv + c4.z, 0.f);
        o.w = fmaxf(acc.w * inv + c4.w, 0.f);
        *(float4*)(hout + (size_t)d * 64 + fg * 4) = o;
    }
}

// ---------------- pooling: grid-stride partial sums + tiny head ----------------

__global__ __launch_bounds__(256) void k_pool_partial(
    const float* __restrict__ h, const int* __restrict__ batch,
    float* __restrict__ sums, int n) {
    int wv = blockIdx.x * (blockDim.x >> 6) + (threadIdx.x >> 6);
    int lane = threadIdx.x & 63;
    int nwv = gridDim.x * (blockDim.x >> 6);
    int chunk = (n + nwv - 1) / nwv;
    int r0 = wv * chunk, r1 = min(n, r0 + chunk);
    if (r0 >= r1) return;
    float acc = 0.f;
    int g = batch[r0];
    for (int r = r0; r < r1; r++) {
        int bg = batch[r];
        if (bg != g) {
            atomicAdd(&sums[g * 64 + lane], acc);
            acc = 0.f;
            g = bg;
        }
        acc += h[(size_t)r * 64 + lane];
    }
    atomicAdd(&sums[g * 64 + lane], acc);
}

__global__ __launch_bounds__(64) void k_head(
    const float* __restrict__ sums, const int* __restrict__ batch,
    const float* __restrict__ Wlin, const float* __restrict__ blin,
    float* __restrict__ out, int n) {
    int g = blockIdx.x;
    int lane = threadIdx.x;
    int lo = 0, hi = n;
    while (lo < hi) { int mid = (lo + hi) >> 1; if (batch[mid] < g) lo = mid + 1; else hi = mid; }
    int start = lo;
    lo = start; hi = n;
    while (lo < hi) { int mid = (lo + hi) >> 1; if (batch[mid] < g + 1) lo = mid + 1; else hi = mid; }
    int cnt = lo - start;
    float pooled = sums[g * 64 + lane] / (float)(cnt > 0 ? cnt : 1);
    float p0 = pooled * Wlin[lane * 2 + 0];
    float p1 = pooled * Wlin[lane * 2 + 1];
    #pragma unroll
    for (int off = 32; off > 0; off >>= 1) {
        p0 += __shfl_xor(p0, off);
        p1 += __shfl_xor(p1, off);
    }
    if (lane == 0) {
        p0 += blin[0]; p1 += blin[1];
        float m = fmaxf(p0, p1);
        float e0 = __expf(p0 - m), e1 = __expf(p1 - m);
        float s = e0 + e1;
        out[g * 2 + 0] = e0 / s;
        out[g * 2 + 1] = e1 / s;
    }
}

// ---------------- launch ----------------

extern "C" void kernel_launch(void* const* d_in, const int* in_sizes, int n_in,
                              void* d_out, int out_size, void* d_ws, size_t ws_size,
                              hipStream_t stream) {
    const float* x      = (const float*)d_in[0];
    const int*   ei     = (const int*)d_in[1];
    const float* euclid = (const float*)d_in[2];
    const int*   batch  = (const int*)d_in[3];
    auto P = [&](int i) { return (const float*)d_in[i]; };

    uintptr_t base = (uintptr_t)d_ws;
    auto carve = [&](size_t bytes) {
        uintptr_t r = base;
        base += (bytes + 255) & ~(size_t)255;
        return (void*)r;
    };
    float* xl      = (float*)carve((size_t)NN * 64 * 4);
    float* xr      = (float*)carve((size_t)NN * 64 * 4);
    float* h1      = (float*)carve((size_t)NN * 64 * 4);
    float* h2      = (float*)carve((size_t)NN * 64 * 4);
    int*   deg     = (int*)carve((size_t)NN * 4);
    int*   offs    = (int*)carve((size_t)(NN + 1) * 4);
    int*   cursor  = (int*)carve((size_t)NN * 4);
    int*   csr_src = (int*)carve((size_t)NE * 4);
    float* csr_w   = (float*)carve((size_t)NE * 4);
    float* gsums   = (float*)carve((size_t)NG * 64 * 4);

    hipMemsetAsync(deg, 0, (size_t)NN * 4, stream);
    hipMemsetAsync(cursor, 0, (size_t)NN * 4, stream);
    hipMemsetAsync(gsums, 0, (size_t)NG * 64 * 4, stream);

    k_degree<<<(NE + 255) / 256, 256, 0, stream>>>(ei + NE, deg, NE);
    k_scan<<<1, 1024, 0, stream>>>(deg, offs, NN);
    k_scatter<<<(NE + 255) / 256, 256, 0, stream>>>(ei, euclid, offs, cursor, csr_src, csr_w, NE);

    int nEdgeBlocks = (NN * 64 + 255) / 256;
    // layer 1: x [NN,128]
    k_gemm<128, 8><<<(NN + 31) / 32, 256, 0, stream>>>(x, P(4), P(5), P(6), P(7), xl, xr, NN);
    k_edge<<<nEdgeBlocks, 256, 0, stream>>>(xl, xr, offs, csr_src, csr_w, P(8), P(9), P(10), h1, NN);
    // layer 2
    k_gemm<64, 8><<<(NN + 31) / 32, 256, 0, stream>>>(h1, P(11), P(12), P(13), P(14), xl, xr, NN);
    k_edge<<<nEdgeBlocks, 256, 0, stream>>>(xl, xr, offs, csr_src, csr_w, P(15), P(16), P(17), h2, NN);
    // layer 3
    k_gemm<64, 8><<<(NN + 31) / 32, 256, 0, stream>>>(h2, P(18), P(19), P(20), P(21), xl, xr, NN);
    k_edge<<<nEdgeBlocks, 256, 0, stream>>>(xl, xr, offs, csr_src, csr_w, P(22), P(23), P(24), h1, NN);

    k_pool_partial<<<256, 256, 0, stream>>>(h1, batch, gsums, NN);
    k_head<<<NG, 64, 0, stream>>>(gsums, batch, P(25), P(26), (float*)d_out, NN);
}

// Round 4
// 391.929 us; speedup vs baseline: 2.3820x; 1.1350x over previous
//
#include <hip/hip_runtime.h>
#include <hip/hip_bf16.h>
#include <cstdint>

#define NN 50000
#define NE 800000
#define NG 64

// ---------------- CSR build ----------------

__global__ void k_degree(const int* __restrict__ dst, int* __restrict__ deg, int E) {
    int i = blockIdx.x * blockDim.x + threadIdx.x;
    if (i < E) atomicAdd(&deg[dst[i]], 1);
}

__global__ void k_scan(const int* __restrict__ deg, int* __restrict__ offs, int n) {
    __shared__ int wsum[16];
    __shared__ int carry_s;
    int tid = threadIdx.x;
    int lane = tid & 63, wv = tid >> 6;
    if (tid == 0) { carry_s = 0; offs[0] = 0; }
    __syncthreads();
    for (int base = 0; base < n; base += 1024) {
        int i = base + tid;
        int v = (i < n) ? deg[i] : 0;
        int s = v;
        #pragma unroll
        for (int off = 1; off < 64; off <<= 1) {
            int t = __shfl_up(s, off);
            if (lane >= off) s += t;
        }
        if (lane == 63) wsum[wv] = s;
        __syncthreads();
        if (wv == 0 && lane < 16) {
            int t = wsum[lane];
            #pragma unroll
            for (int off = 1; off < 16; off <<= 1) {
                int u = __shfl_up(t, off);
                if (lane >= off) t += u;
            }
            wsum[lane] = t;
        }
        __syncthreads();
        int wpre = (wv == 0) ? 0 : wsum[wv - 1];
        int total = wsum[15];
        int c0 = carry_s;
        if (i < n) offs[i + 1] = c0 + wpre + s;
        __syncthreads();
        if (tid == 0) carry_s = c0 + total;
        __syncthreads();
    }
}

__global__ void k_scatter(const int* __restrict__ ei, const float* __restrict__ euclid,
                          const int* __restrict__ offs, int* __restrict__ cursor,
                          int* __restrict__ csr_src, float* __restrict__ csr_w, int E) {
    int e = blockIdx.x * blockDim.x + threadIdx.x;
    if (e < E) {
        int s = ei[e];
        int d = ei[NE + e];
        int pos = offs[d] + atomicAdd(&cursor[d], 1);
        csr_src[pos] = s;
        csr_w[pos] = euclid[e];
    }
}

// ---------------- tiled dual SGEMM: [n x DIN] @ [DIN x 64]x2 -----------------
// BM=128 rows, BN=128 (cols 0-63 -> Wl/xl, 64-127 -> Wr/xr), BK=16.
// 256 threads, per-thread 8x8 register tile. X tile transposed in LDS
// (stride 132: 16B-aligned reads, spread write banks). Double-buffered.

template <int DIN>
__global__ __launch_bounds__(256) void k_gemm2(
    const float* __restrict__ X,
    const float* __restrict__ Wl, const float* __restrict__ bl,
    const float* __restrict__ Wr, const float* __restrict__ br,
    float* __restrict__ xl, float* __restrict__ xr, int n) {
    constexpr int BK = 16, BM = 128, XS = BM + 4;  // 132
    constexpr int NKT = DIN / BK;
    __shared__ float sX[2][BK][XS];
    __shared__ float sW[2][BK][128];
    int t = threadIdx.x;
    int rb = blockIdx.x * BM;

    // staging coordinates
    int xrow = t >> 2, xk4 = (t & 3) << 2;          // X: 64 rows x 4 k-quads per pass
    int wk = t >> 5, wcol = (t & 31) << 2;          // W: 8 k-rows x 32 col-quads
    int r0g = min(rb + xrow, n - 1);
    int r1g = min(rb + 64 + xrow, n - 1);
    const float* xp0 = X + (size_t)r0g * DIN + xk4;
    const float* xp1 = X + (size_t)r1g * DIN + xk4;
    const float* wsrc0 = (wcol < 64) ? (Wl + wk * 64 + wcol) : (Wr + wk * 64 + wcol - 64);
    const float* wsrc1 = (wcol < 64) ? (Wl + (wk + 8) * 64 + wcol) : (Wr + (wk + 8) * 64 + wcol - 64);

    float4 gx0 = *(const float4*)xp0;
    float4 gx1 = *(const float4*)xp1;
    float4 gw0 = *(const float4*)wsrc0;
    float4 gw1 = *(const float4*)wsrc1;

    auto writeTile = [&](int b) {
        #pragma unroll
        for (int i = 0; i < 4; i++) {
            sX[b][xk4 + i][xrow]      = (&gx0.x)[i];
            sX[b][xk4 + i][64 + xrow] = (&gx1.x)[i];
        }
        *(float4*)&sW[b][wk][wcol]     = gw0;
        *(float4*)&sW[b][wk + 8][wcol] = gw1;
    };
    writeTile(0);
    __syncthreads();

    int tx = t & 15, ty = t >> 4;   // 16x16 thread grid
    int r0 = ty * 4;                 // rows r0..r0+3 and 64+r0..64+r0+3
    int c0 = tx * 4;                 // xl cols c0..c0+3 ; xr cols via sW col 64+c0
    float acc[8][8];
    #pragma unroll
    for (int i = 0; i < 8; i++)
        #pragma unroll
        for (int j = 0; j < 8; j++) acc[i][j] = 0.f;

    for (int kt = 0; kt < NKT; ++kt) {
        int cur = kt & 1;
        if (kt + 1 < NKT) {
            gx0 = *(const float4*)(xp0 + (kt + 1) * BK);
            gx1 = *(const float4*)(xp1 + (kt + 1) * BK);
            gw0 = *(const float4*)(wsrc0 + (size_t)(kt + 1) * BK * 64);
            gw1 = *(const float4*)(wsrc1 + (size_t)(kt + 1) * BK * 64);
        }
        #pragma unroll
        for (int k = 0; k < BK; k++) {
            float4 xa = *(const float4*)&sX[cur][k][r0];
            float4 xb = *(const float4*)&sX[cur][k][64 + r0];
            float4 wa = *(const float4*)&sW[cur][k][c0];
            float4 wb = *(const float4*)&sW[cur][k][64 + c0];
            float xv[8] = {xa.x, xa.y, xa.z, xa.w, xb.x, xb.y, xb.z, xb.w};
            float wv[8] = {wa.x, wa.y, wa.z, wa.w, wb.x, wb.y, wb.z, wb.w};
            #pragma unroll
            for (int ri = 0; ri < 8; ri++)
                #pragma unroll
                for (int cj = 0; cj < 8; cj++) acc[ri][cj] += xv[ri] * wv[cj];
        }
        if (kt + 1 < NKT) writeTile((kt + 1) & 1);
        __syncthreads();
    }

    float4 bl4 = *(const float4*)(bl + c0);
    float4 br4 = *(const float4*)(br + c0);
    #pragma unroll
    for (int ri = 0; ri < 8; ri++) {
        int row = rb + ((ri < 4) ? (r0 + ri) : (64 + r0 + ri - 4));
        if (row < n) {
            float4 ol, orr;
            ol.x = acc[ri][0] + bl4.x; ol.y = acc[ri][1] + bl4.y;
            ol.z = acc[ri][2] + bl4.z; ol.w = acc[ri][3] + bl4.w;
            orr.x = acc[ri][4] + br4.x; orr.y = acc[ri][5] + br4.y;
            orr.z = acc[ri][6] + br4.z; orr.w = acc[ri][7] + br4.w;
            *(float4*)(xl + (size_t)row * 64 + c0) = ol;
            *(float4*)(xr + (size_t)row * 64 + c0) = orr;
        }
    }
}

// ---------------- edge kernel: one wave per dst node, 4 edges x 16 lanes ----

__global__ __launch_bounds__(256) void k_edge(
    const float* __restrict__ xl, const float* __restrict__ xr,
    const int* __restrict__ offs, const int* __restrict__ csr_src,
    const float* __restrict__ csr_w,
    const float* __restrict__ We, const float* __restrict__ att,
    const float* __restrict__ cb, float* __restrict__ hout, int n) {
    const float NEGBIG = -1e30f;
    int gtid = blockIdx.x * blockDim.x + threadIdx.x;
    int d = gtid >> 6;
    if (d >= n) return;
    int lane = threadIdx.x & 63;
    int fg = lane & 15;   // feature quad index
    int eg = lane >> 4;   // edge sub-slot 0..3

    float4 c4 = *(const float4*)(cb + fg * 4);
    int s0 = offs[d], s1 = offs[d + 1];
    int deg = s1 - s0;
    if (deg == 0) {
        if (eg == 0) {
            float4 o = make_float4(fmaxf(c4.x, 0.f), fmaxf(c4.y, 0.f),
                                   fmaxf(c4.z, 0.f), fmaxf(c4.w, 0.f));
            *(float4*)(hout + (size_t)d * 64 + fg * 4) = o;
        }
        return;
    }
    float4 xr4 = *(const float4*)(xr + (size_t)d * 64 + fg * 4);
    float4 We4 = *(const float4*)(We + fg * 4);
    float4 at4 = *(const float4*)(att + fg * 4);

    float mx = NEGBIG, sum = 0.f;
    float4 acc = make_float4(0.f, 0.f, 0.f, 0.f);

    for (int base = 0; base < deg; base += 4) {
        int idx = base + eg;
        bool valid = idx < deg;
        int e = s0 + (valid ? idx : deg - 1);
        int s = csr_src[e];
        float w = csr_w[e];
        float4 xl4 = *(const float4*)(xl + (size_t)s * 64 + fg * 4);
        float mA = xl4.x + xr4.x + w * We4.x;
        float mB = xl4.y + xr4.y + w * We4.y;
        float mC = xl4.z + xr4.z + w * We4.z;
        float mD = xl4.w + xr4.w + w * We4.w;
        mA = (mA > 0.f ? mA : 0.2f * mA);
        mB = (mB > 0.f ? mB : 0.2f * mB);
        mC = (mC > 0.f ? mC : 0.2f * mC);
        mD = (mD > 0.f ? mD : 0.2f * mD);
        float p = mA * at4.x + mB * at4.y + mC * at4.z + mD * at4.w;
        #pragma unroll
        for (int off = 1; off < 16; off <<= 1) p += __shfl_xor(p, off);
        float nm = fmaxf(mx, valid ? p : NEGBIG);
        float f = __expf(mx - nm);
        float wp = valid ? __expf(p - nm) : 0.f;
        acc.x = acc.x * f + wp * xl4.x;
        acc.y = acc.y * f + wp * xl4.y;
        acc.z = acc.z * f + wp * xl4.z;
        acc.w = acc.w * f + wp * xl4.w;
        sum = sum * f + wp;
        mx = nm;
    }

    #pragma unroll
    for (int off = 16; off <= 32; off <<= 1) {
        float omx = __shfl_xor(mx, off);
        float osum = __shfl_xor(sum, off);
        float oax = __shfl_xor(acc.x, off);
        float oay = __shfl_xor(acc.y, off);
        float oaz = __shfl_xor(acc.z, off);
        float oaw = __shfl_xor(acc.w, off);
        float nm = fmaxf(mx, omx);
        float f1 = __expf(mx - nm);
        float f2 = __expf(omx - nm);
        acc.x = acc.x * f1 + oax * f2;
        acc.y = acc.y * f1 + oay * f2;
        acc.z = acc.z * f1 + oaz * f2;
        acc.w = acc.w * f1 + oaw * f2;
        sum = sum * f1 + osum * f2;
        mx = nm;
    }

    if (eg == 0) {
        float inv = 1.0f / sum;
        float4 o;
        o.x = fmaxf(acc.x * inv + c4.x, 0.f);
        o.y = fmaxf(acc.y * inv + c4.y, 0.f);
        o.z = fmaxf(acc.z * inv + c4.z, 0.f);
        o.w = fmaxf(acc.w * inv + c4.w, 0.f);
        *(float4*)(hout + (size_t)d * 64 + fg * 4) = o;
    }
}

// ---------------- pooling: grid-stride partial sums + tiny head ----------------

__global__ __launch_bounds__(256) void k_pool_partial(
    const float* __restrict__ h, const int* __restrict__ batch,
    float* __restrict__ sums, int n) {
    int wv = blockIdx.x * (blockDim.x >> 6) + (threadIdx.x >> 6);
    int lane = threadIdx.x & 63;
    int nwv = gridDim.x * (blockDim.x >> 6);
    int chunk = (n + nwv - 1) / nwv;
    int r0 = wv * chunk, r1 = min(n, r0 + chunk);
    if (r0 >= r1) return;
    float acc = 0.f;
    int g = batch[r0];
    for (int r = r0; r < r1; r++) {
        int bg = batch[r];
        if (bg != g) {
            atomicAdd(&sums[g * 64 + lane], acc);
            acc = 0.f;
            g = bg;
        }
        acc += h[(size_t)r * 64 + lane];
    }
    atomicAdd(&sums[g * 64 + lane], acc);
}

__global__ __launch_bounds__(64) void k_head(
    const float* __restrict__ sums, const int* __restrict__ batch,
    const float* __restrict__ Wlin, const float* __restrict__ blin,
    float* __restrict__ out, int n) {
    int g = blockIdx.x;
    int lane = threadIdx.x;
    int lo = 0, hi = n;
    while (lo < hi) { int mid = (lo + hi) >> 1; if (batch[mid] < g) lo = mid + 1; else hi = mid; }
    int start = lo;
    lo = start; hi = n;
    while (lo < hi) { int mid = (lo + hi) >> 1; if (batch[mid] < g + 1) lo = mid + 1; else hi = mid; }
    int cnt = lo - start;
    float pooled = sums[g * 64 + lane] / (float)(cnt > 0 ? cnt : 1);
    float p0 = pooled * Wlin[lane * 2 + 0];
    float p1 = pooled * Wlin[lane * 2 + 1];
    #pragma unroll
    for (int off = 32; off > 0; off >>= 1) {
        p0 += __shfl_xor(p0, off);
        p1 += __shfl_xor(p1, off);
    }
    if (lane == 0) {
        p0 += blin[0]; p1 += blin[1];
        float m = fmaxf(p0, p1);
        float e0 = __expf(p0 - m), e1 = __expf(p1 - m);
        float s = e0 + e1;
        out[g * 2 + 0] = e0 / s;
        out[g * 2 + 1] = e1 / s;
    }
}

// ---------------- launch ----------------

extern "C" void kernel_launch(void* const* d_in, const int* in_sizes, int n_in,
                              void* d_out, int out_size, void* d_ws, size_t ws_size,
                              hipStream_t stream) {
    const float* x      = (const float*)d_in[0];
    const int*   ei     = (const int*)d_in[1];
    const float* euclid = (const float*)d_in[2];
    const int*   batch  = (const int*)d_in[3];
    auto P = [&](int i) { return (const float*)d_in[i]; };

    uintptr_t base = (uintptr_t)d_ws;
    auto carve = [&](size_t bytes) {
        uintptr_t r = base;
        base += (bytes + 255) & ~(size_t)255;
        return (void*)r;
    };
    float* xl      = (float*)carve((size_t)NN * 64 * 4);
    float* xr      = (float*)carve((size_t)NN * 64 * 4);
    float* h1      = (float*)carve((size_t)NN * 64 * 4);
    float* h2      = (float*)carve((size_t)NN * 64 * 4);
    int*   deg     = (int*)carve((size_t)NN * 4);
    int*   offs    = (int*)carve((size_t)(NN + 1) * 4);
    int*   cursor  = (int*)carve((size_t)NN * 4);
    int*   csr_src = (int*)carve((size_t)NE * 4);
    float* csr_w   = (float*)carve((size_t)NE * 4);
    float* gsums   = (float*)carve((size_t)NG * 64 * 4);

    hipMemsetAsync(deg, 0, (size_t)NN * 4, stream);
    hipMemsetAsync(cursor, 0, (size_t)NN * 4, stream);
    hipMemsetAsync(gsums, 0, (size_t)NG * 64 * 4, stream);

    k_degree<<<(NE + 255) / 256, 256, 0, stream>>>(ei + NE, deg, NE);
    k_scan<<<1, 1024, 0, stream>>>(deg, offs, NN);
    k_scatter<<<(NE + 255) / 256, 256, 0, stream>>>(ei, euclid, offs, cursor, csr_src, csr_w, NE);

    int nEdgeBlocks = (NN * 64 + 255) / 256;
    int nGemmBlocks = (NN + 127) / 128;
    // layer 1: x [NN,128]
    k_gemm2<128><<<nGemmBlocks, 256, 0, stream>>>(x, P(4), P(5), P(6), P(7), xl, xr, NN);
    k_edge<<<nEdgeBlocks, 256, 0, stream>>>(xl, xr, offs, csr_src, csr_w, P(8), P(9), P(10), h1, NN);
    // layer 2
    k_gemm2<64><<<nGemmBlocks, 256, 0, stream>>>(h1, P(11), P(12), P(13), P(14), xl, xr, NN);
    k_edge<<<nEdgeBlocks, 256, 0, stream>>>(xl, xr, offs, csr_src, csr_w, P(15), P(16), P(17), h2, NN);
    // layer 3
    k_gemm2<64><<<nGemmBlocks, 256, 0, stream>>>(h2, P(18), P(19), P(20), P(21), xl, xr, NN);
    k_edge<<<nEdgeBlocks, 256, 0, stream>>>(xl, xr, offs, csr_src, csr_w, P(22), P(23), P(24), h1, NN);

    k_pool_partial<<<256, 256, 0, stream>>>(h1, batch, gsums, NN);
    k_head<<<NG, 64, 0, stream>>>(gsums, batch, P(25), P(26), (float*)d_out, NN);
}

// Round 5
// 382.237 us; speedup vs baseline: 2.4424x; 1.0254x over previous
//
#include <hip/hip_runtime.h>
#include <hip/hip_bf16.h>
#include <hip/hip_fp16.h>
#include <cstdint>

#define NN 50000
#define NE 800000
#define NG 64

// ---------------- CSR build ----------------

__global__ void k_degree(const int* __restrict__ dst, int* __restrict__ deg, int E) {
    int i = blockIdx.x * blockDim.x + threadIdx.x;
    if (i < E) atomicAdd(&deg[dst[i]], 1);
}

__global__ void k_scan(const int* __restrict__ deg, int* __restrict__ offs, int n) {
    __shared__ int wsum[16];
    __shared__ int carry_s;
    int tid = threadIdx.x;
    int lane = tid & 63, wv = tid >> 6;
    if (tid == 0) { carry_s = 0; offs[0] = 0; }
    __syncthreads();
    for (int base = 0; base < n; base += 1024) {
        int i = base + tid;
        int v = (i < n) ? deg[i] : 0;
        int s = v;
        #pragma unroll
        for (int off = 1; off < 64; off <<= 1) {
            int t = __shfl_up(s, off);
            if (lane >= off) s += t;
        }
        if (lane == 63) wsum[wv] = s;
        __syncthreads();
        if (wv == 0 && lane < 16) {
            int t = wsum[lane];
            #pragma unroll
            for (int off = 1; off < 16; off <<= 1) {
                int u = __shfl_up(t, off);
                if (lane >= off) t += u;
            }
            wsum[lane] = t;
        }
        __syncthreads();
        int wpre = (wv == 0) ? 0 : wsum[wv - 1];
        int total = wsum[15];
        int c0 = carry_s;
        if (i < n) offs[i + 1] = c0 + wpre + s;
        __syncthreads();
        if (tid == 0) carry_s = c0 + total;
        __syncthreads();
    }
}

// packed CSR entry: low 16 bits = src node id (< 65536), high 16 = w in u16
// fixed point over [0,1] (quantization error <= 8e-6, threshold is 1e-2).
__global__ void k_scatter(const int* __restrict__ ei, const float* __restrict__ euclid,
                          const int* __restrict__ offs, int* __restrict__ cursor,
                          uint32_t* __restrict__ csr, int E) {
    int e = blockIdx.x * blockDim.x + threadIdx.x;
    if (e < E) {
        int s = ei[e];
        int d = ei[NE + e];
        uint32_t wq = __float2uint_rn(euclid[e] * 65535.0f);
        int pos = offs[d] + atomicAdd(&cursor[d], 1);
        csr[pos] = (wq << 16) | (uint32_t)s;
    }
}

// ---------------- tiled dual SGEMM: [n x DIN] @ [DIN x 64]x2 -----------------
// BM=128, BN=128 (cols 0-63 -> Wl/xl, 64-127 -> Wr/xr), BK=16, 256 threads,
// 8x8 register tile, double-buffered. xl written as fp16 (gather table),
// xr as fp32.

template <int DIN>
__global__ __launch_bounds__(256) void k_gemm2(
    const float* __restrict__ X,
    const float* __restrict__ Wl, const float* __restrict__ bl,
    const float* __restrict__ Wr, const float* __restrict__ br,
    __half* __restrict__ xlh, float* __restrict__ xr, int n) {
    constexpr int BK = 16, BM = 128, XS = BM + 4;  // 132
    constexpr int NKT = DIN / BK;
    __shared__ float sX[2][BK][XS];
    __shared__ float sW[2][BK][128];
    int t = threadIdx.x;
    int rb = blockIdx.x * BM;

    int xrow = t >> 2, xk4 = (t & 3) << 2;
    int wk = t >> 5, wcol = (t & 31) << 2;
    int r0g = min(rb + xrow, n - 1);
    int r1g = min(rb + 64 + xrow, n - 1);
    const float* xp0 = X + (size_t)r0g * DIN + xk4;
    const float* xp1 = X + (size_t)r1g * DIN + xk4;
    const float* wsrc0 = (wcol < 64) ? (Wl + wk * 64 + wcol) : (Wr + wk * 64 + wcol - 64);
    const float* wsrc1 = (wcol < 64) ? (Wl + (wk + 8) * 64 + wcol) : (Wr + (wk + 8) * 64 + wcol - 64);

    float4 gx0 = *(const float4*)xp0;
    float4 gx1 = *(const float4*)xp1;
    float4 gw0 = *(const float4*)wsrc0;
    float4 gw1 = *(const float4*)wsrc1;

    auto writeTile = [&](int b) {
        #pragma unroll
        for (int i = 0; i < 4; i++) {
            sX[b][xk4 + i][xrow]      = (&gx0.x)[i];
            sX[b][xk4 + i][64 + xrow] = (&gx1.x)[i];
        }
        *(float4*)&sW[b][wk][wcol]     = gw0;
        *(float4*)&sW[b][wk + 8][wcol] = gw1;
    };
    writeTile(0);
    __syncthreads();

    int tx = t & 15, ty = t >> 4;
    int r0 = ty * 4;
    int c0 = tx * 4;
    float acc[8][8];
    #pragma unroll
    for (int i = 0; i < 8; i++)
        #pragma unroll
        for (int j = 0; j < 8; j++) acc[i][j] = 0.f;

    for (int kt = 0; kt < NKT; ++kt) {
        int cur = kt & 1;
        if (kt + 1 < NKT) {
            gx0 = *(const float4*)(xp0 + (kt + 1) * BK);
            gx1 = *(const float4*)(xp1 + (kt + 1) * BK);
            gw0 = *(const float4*)(wsrc0 + (size_t)(kt + 1) * BK * 64);
            gw1 = *(const float4*)(wsrc1 + (size_t)(kt + 1) * BK * 64);
        }
        #pragma unroll
        for (int k = 0; k < BK; k++) {
            float4 xa = *(const float4*)&sX[cur][k][r0];
            float4 xb = *(const float4*)&sX[cur][k][64 + r0];
            float4 wa = *(const float4*)&sW[cur][k][c0];
            float4 wb = *(const float4*)&sW[cur][k][64 + c0];
            float xv[8] = {xa.x, xa.y, xa.z, xa.w, xb.x, xb.y, xb.z, xb.w};
            float wv[8] = {wa.x, wa.y, wa.z, wa.w, wb.x, wb.y, wb.z, wb.w};
            #pragma unroll
            for (int ri = 0; ri < 8; ri++)
                #pragma unroll
                for (int cj = 0; cj < 8; cj++) acc[ri][cj] += xv[ri] * wv[cj];
        }
        if (kt + 1 < NKT) writeTile((kt + 1) & 1);
        __syncthreads();
    }

    float4 bl4 = *(const float4*)(bl + c0);
    float4 br4 = *(const float4*)(br + c0);
    #pragma unroll
    for (int ri = 0; ri < 8; ri++) {
        int row = rb + ((ri < 4) ? (r0 + ri) : (64 + r0 + ri - 4));
        if (row < n) {
            __half2 ha = __floats2half2_rn(acc[ri][0] + bl4.x, acc[ri][1] + bl4.y);
            __half2 hb = __floats2half2_rn(acc[ri][2] + bl4.z, acc[ri][3] + bl4.w);
            uint2 uo;
            uo.x = *reinterpret_cast<uint32_t*>(&ha);
            uo.y = *reinterpret_cast<uint32_t*>(&hb);
            *(uint2*)(xlh + (size_t)row * 64 + c0) = uo;
            float4 orr;
            orr.x = acc[ri][4] + br4.x; orr.y = acc[ri][5] + br4.y;
            orr.z = acc[ri][6] + br4.z; orr.w = acc[ri][7] + br4.w;
            *(float4*)(xr + (size_t)row * 64 + c0) = orr;
        }
    }
}

// ---------------- edge kernel: one wave per dst node, 4 edges x 16 lanes ----
// fp16 gather table (128 B/row), packed 4B CSR entry.

__global__ __launch_bounds__(256) void k_edge(
    const __half* __restrict__ xlh, const float* __restrict__ xr,
    const int* __restrict__ offs, const uint32_t* __restrict__ csr,
    const float* __restrict__ We, const float* __restrict__ att,
    const float* __restrict__ cb, float* __restrict__ hout, int n) {
    const float NEGBIG = -1e30f;
    int gtid = blockIdx.x * blockDim.x + threadIdx.x;
    int d = gtid >> 6;
    if (d >= n) return;
    int lane = threadIdx.x & 63;
    int fg = lane & 15;
    int eg = lane >> 4;

    float4 c4 = *(const float4*)(cb + fg * 4);
    int s0 = offs[d], s1 = offs[d + 1];
    int deg = s1 - s0;
    if (deg == 0) {
        if (eg == 0) {
            float4 o = make_float4(fmaxf(c4.x, 0.f), fmaxf(c4.y, 0.f),
                                   fmaxf(c4.z, 0.f), fmaxf(c4.w, 0.f));
            *(float4*)(hout + (size_t)d * 64 + fg * 4) = o;
        }
        return;
    }
    float4 xr4 = *(const float4*)(xr + (size_t)d * 64 + fg * 4);
    float4 We4 = *(const float4*)(We + fg * 4);
    float4 at4 = *(const float4*)(att + fg * 4);

    float mx = NEGBIG, sum = 0.f;
    float4 acc = make_float4(0.f, 0.f, 0.f, 0.f);

    for (int base = 0; base < deg; base += 4) {
        int idx = base + eg;
        bool valid = idx < deg;
        int e = s0 + (valid ? idx : deg - 1);
        uint32_t ent = csr[e];
        int s = ent & 0xFFFF;
        float w = (float)(ent >> 16) * (1.0f / 65535.0f);
        uint2 raw = *(const uint2*)(xlh + (size_t)s * 64 + fg * 4);
        float2 f0 = __half22float2(*reinterpret_cast<const __half2*>(&raw.x));
        float2 f1 = __half22float2(*reinterpret_cast<const __half2*>(&raw.y));
        float mA = f0.x + xr4.x + w * We4.x;
        float mB = f0.y + xr4.y + w * We4.y;
        float mC = f1.x + xr4.z + w * We4.z;
        float mD = f1.y + xr4.w + w * We4.w;
        mA = (mA > 0.f ? mA : 0.2f * mA);
        mB = (mB > 0.f ? mB : 0.2f * mB);
        mC = (mC > 0.f ? mC : 0.2f * mC);
        mD = (mD > 0.f ? mD : 0.2f * mD);
        float p = mA * at4.x + mB * at4.y + mC * at4.z + mD * at4.w;
        #pragma unroll
        for (int off = 1; off < 16; off <<= 1) p += __shfl_xor(p, off);
        float nm = fmaxf(mx, valid ? p : NEGBIG);
        float f = __expf(mx - nm);
        float wp = valid ? __expf(p - nm) : 0.f;
        acc.x = acc.x * f + wp * f0.x;
        acc.y = acc.y * f + wp * f0.y;
        acc.z = acc.z * f + wp * f1.x;
        acc.w = acc.w * f + wp * f1.y;
        sum = sum * f + wp;
        mx = nm;
    }

    #pragma unroll
    for (int off = 16; off <= 32; off <<= 1) {
        float omx = __shfl_xor(mx, off);
        float osum = __shfl_xor(sum, off);
        float oax = __shfl_xor(acc.x, off);
        float oay = __shfl_xor(acc.y, off);
        float oaz = __shfl_xor(acc.z, off);
        float oaw = __shfl_xor(acc.w, off);
        float nm = fmaxf(mx, omx);
        float f1 = __expf(mx - nm);
        float f2 = __expf(omx - nm);
        acc.x = acc.x * f1 + oax * f2;
        acc.y = acc.y * f1 + oay * f2;
        acc.z = acc.z * f1 + oaz * f2;
        acc.w = acc.w * f1 + oaw * f2;
        sum = sum * f1 + osum * f2;
        mx = nm;
    }

    if (eg == 0) {
        float inv = 1.0f / sum;
        float4 o;
        o.x = fmaxf(acc.x * inv + c4.x, 0.f);
        o.y = fmaxf(acc.y * inv + c4.y, 0.f);
        o.z = fmaxf(acc.z * inv + c4.z, 0.f);
        o.w = fmaxf(acc.w * inv + c4.w, 0.f);
        *(float4*)(hout + (size_t)d * 64 + fg * 4) = o;
    }
}

// ---------------- pooling: grid-stride partial sums + tiny head ----------------

__global__ __launch_bounds__(256) void k_pool_partial(
    const float* __restrict__ h, const int* __restrict__ batch,
    float* __restrict__ sums, int n) {
    int wv = blockIdx.x * (blockDim.x >> 6) + (threadIdx.x >> 6);
    int lane = threadIdx.x & 63;
    int nwv = gridDim.x * (blockDim.x >> 6);
    int chunk = (n + nwv - 1) / nwv;
    int r0 = wv * chunk, r1 = min(n, r0 + chunk);
    if (r0 >= r1) return;
    float acc = 0.f;
    int g = batch[r0];
    for (int r = r0; r < r1; r++) {
        int bg = batch[r];
        if (bg != g) {
            atomicAdd(&sums[g * 64 + lane], acc);
            acc = 0.f;
            g = bg;
        }
        acc += h[(size_t)r * 64 + lane];
    }
    atomicAdd(&sums[g * 64 + lane], acc);
}

__global__ __launch_bounds__(64) void k_head(
    const float* __restrict__ sums, const int* __restrict__ batch,
    const float* __restrict__ Wlin, const float* __restrict__ blin,
    float* __restrict__ out, int n) {
    int g = blockIdx.x;
    int lane = threadIdx.x;
    int lo = 0, hi = n;
    while (lo < hi) { int mid = (lo + hi) >> 1; if (batch[mid] < g) lo = mid + 1; else hi = mid; }
    int start = lo;
    lo = start; hi = n;
    while (lo < hi) { int mid = (lo + hi) >> 1; if (batch[mid] < g + 1) lo = mid + 1; else hi = mid; }
    int cnt = lo - start;
    float pooled = sums[g * 64 + lane] / (float)(cnt > 0 ? cnt : 1);
    float p0 = pooled * Wlin[lane * 2 + 0];
    float p1 = pooled * Wlin[lane * 2 + 1];
    #pragma unroll
    for (int off = 32; off > 0; off >>= 1) {
        p0 += __shfl_xor(p0, off);
        p1 += __shfl_xor(p1, off);
    }
    if (lane == 0) {
        p0 += blin[0]; p1 += blin[1];
        float m = fmaxf(p0, p1);
        float e0 = __expf(p0 - m), e1 = __expf(p1 - m);
        float s = e0 + e1;
        out[g * 2 + 0] = e0 / s;
        out[g * 2 + 1] = e1 / s;
    }
}

// ---------------- launch ----------------

extern "C" void kernel_launch(void* const* d_in, const int* in_sizes, int n_in,
                              void* d_out, int out_size, void* d_ws, size_t ws_size,
                              hipStream_t stream) {
    const float* x      = (const float*)d_in[0];
    const int*   ei     = (const int*)d_in[1];
    const float* euclid = (const float*)d_in[2];
    const int*   batch  = (const int*)d_in[3];
    auto P = [&](int i) { return (const float*)d_in[i]; };

    uintptr_t base = (uintptr_t)d_ws;
    auto carve = [&](size_t bytes) {
        uintptr_t r = base;
        base += (bytes + 255) & ~(size_t)255;
        return (void*)r;
    };
    __half* xlh    = (__half*)carve((size_t)NN * 64 * 2);
    float* xr      = (float*)carve((size_t)NN * 64 * 4);
    float* h1      = (float*)carve((size_t)NN * 64 * 4);
    float* h2      = (float*)carve((size_t)NN * 64 * 4);
    int*   deg     = (int*)carve((size_t)NN * 4);
    int*   offs    = (int*)carve((size_t)(NN + 1) * 4);
    int*   cursor  = (int*)carve((size_t)NN * 4);
    uint32_t* csr  = (uint32_t*)carve((size_t)NE * 4);
    float* gsums   = (float*)carve((size_t)NG * 64 * 4);

    hipMemsetAsync(deg, 0, (size_t)NN * 4, stream);
    hipMemsetAsync(cursor, 0, (size_t)NN * 4, stream);
    hipMemsetAsync(gsums, 0, (size_t)NG * 64 * 4, stream);

    k_degree<<<(NE + 255) / 256, 256, 0, stream>>>(ei + NE, deg, NE);
    k_scan<<<1, 1024, 0, stream>>>(deg, offs, NN);
    k_scatter<<<(NE + 255) / 256, 256, 0, stream>>>(ei, euclid, offs, cursor, csr, NE);

    int nEdgeBlocks = (NN * 64 + 255) / 256;
    int nGemmBlocks = (NN + 127) / 128;
    // layer 1: x [NN,128]
    k_gemm2<128><<<nGemmBlocks, 256, 0, stream>>>(x, P(4), P(5), P(6), P(7), xlh, xr, NN);
    k_edge<<<nEdgeBlocks, 256, 0, stream>>>(xlh, xr, offs, csr, P(8), P(9), P(10), h1, NN);
    // layer 2
    k_gemm2<64><<<nGemmBlocks, 256, 0, stream>>>(h1, P(11), P(12), P(13), P(14), xlh, xr, NN);
    k_edge<<<nEdgeBlocks, 256, 0, stream>>>(xlh, xr, offs, csr, P(15), P(16), P(17), h2, NN);
    // layer 3
    k_gemm2<64><<<nGemmBlocks, 256, 0, stream>>>(h2, P(18), P(19), P(20), P(21), xlh, xr, NN);
    k_edge<<<nEdgeBlocks, 256, 0, stream>>>(xlh, xr, offs, csr, P(22), P(23), P(24), h1, NN);

    k_pool_partial<<<256, 256, 0, stream>>>(h1, batch, gsums, NN);
    k_head<<<NG, 64, 0, stream>>>(gsums, batch, P(25), P(26), (float*)d_out, NN);
}